// Round 6
// baseline (2541.742 us; speedup 1.0000x reference)
//
#include <hip/hip_runtime.h>

typedef unsigned short u16;
typedef __attribute__((ext_vector_type(4))) float   f32x4;
typedef __attribute__((ext_vector_type(8))) __bf16  bf16x8;
typedef __attribute__((ext_vector_type(4))) __bf16  bf16x4;
typedef __attribute__((ext_vector_type(8))) short   short8;
typedef __attribute__((ext_vector_type(4))) int     int32x4;
typedef __attribute__((ext_vector_type(4))) short   short4v;

#define MFMA16(a,b,c) __builtin_amdgcn_mfma_f32_16x16x32_bf16(a,b,c,0,0,0)

static __device__ __forceinline__ u16 f2bf(float f){
  unsigned u = __builtin_bit_cast(unsigned, f);
  return (u16)((u + 0x7fffu + ((u >> 16) & 1u)) >> 16);
}
static __device__ __forceinline__ float bf2f(u16 h){
  return __builtin_bit_cast(float, ((unsigned)h) << 16);
}
static __device__ __forceinline__ bf16x8 ldb16(const u16* p){
  return __builtin_bit_cast(bf16x8, *(const short8*)p);
}
static __device__ __forceinline__ void gload_lds16(const void* g, void* l){
  __builtin_amdgcn_global_load_lds(
      reinterpret_cast<const __attribute__((address_space(1))) unsigned int*>(
          reinterpret_cast<unsigned long long>(g)),
      reinterpret_cast<__attribute__((address_space(3))) unsigned int*>(
          reinterpret_cast<unsigned long long>(l)),
      16, 0, 0);
}

static constexpr int T_ = 1024, H_ = 4096, NH_ = 32, NKV_ = 8, I_ = 12288;

// ---------------- fused (optional add) + RMSNorm over H=4096, bf16 out ----------------
__global__ __launch_bounds__(256) void addnorm_kernel(
    const float* __restrict__ a, const float* __restrict__ b,
    const float* __restrict__ w, float* __restrict__ res_out,
    u16* __restrict__ x_out)
{
  const int t = blockIdx.x, tid = threadIdx.x;
  __shared__ float red[4];
  float vals[16]; float ss = 0.f;
  const size_t base = (size_t)t * H_;
  #pragma unroll
  for (int i = 0; i < 16; ++i){
    int c = tid + i*256;
    float v = a[base + c];
    if (b) v += b[base + c];
    vals[i] = v; ss += v*v;
  }
  #pragma unroll
  for (int off = 32; off; off >>= 1) ss += __shfl_xor(ss, off);
  if ((tid & 63) == 0) red[tid >> 6] = ss;
  __syncthreads();
  float tot = red[0] + red[1] + red[2] + red[3];
  float rn = rsqrtf(tot / (float)H_ + 1e-6f);
  #pragma unroll
  for (int i = 0; i < 16; ++i){
    int c = tid + i*256;
    if (res_out) res_out[base + c] = vals[i];
    x_out[base + c] = f2bf(vals[i] * rn * w[c]);
  }
}

// ---------------- block-diagonal rotation ----------------
__global__ __launch_bounds__(256) void rot_kernel(
    const u16* __restrict__ X, const float* __restrict__ R,
    u16* __restrict__ Y, int LD)
{
  __shared__ u16 sX[64][136];
  __shared__ u16 sRt[128][136];   // sRt[j][i] = R[g][i][j]
  const int g = blockIdx.y, m0 = blockIdx.x * 64, tid = threadIdx.x;
  #pragma unroll
  for (int i = 0; i < 4; ++i){
    int vid = i*256 + tid, r = vid >> 4, c = (vid & 15) * 8;
    *(short8*)&sX[r][c] = *(const short8*)&X[(size_t)(m0 + r) * LD + g*128 + c];
  }
  const float* Rg = R + (size_t)g * 16384;
  #pragma unroll
  for (int it = 0; it < 16; ++it){
    int idx = it*256 + tid;
    int i = idx >> 5, j4 = (idx & 31) * 4;
    float4 v = *(const float4*)&Rg[i*128 + j4];
    sRt[j4  ][i] = f2bf(v.x);
    sRt[j4+1][i] = f2bf(v.y);
    sRt[j4+2][i] = f2bf(v.z);
    sRt[j4+3][i] = f2bf(v.w);
  }
  __syncthreads();
  const int lane = tid & 63, w = tid >> 6;
  const int fr = lane & 15, fq = lane >> 4, nw = w * 32;
  f32x4 acc[4][2];
  #pragma unroll
  for (int mi=0;mi<4;mi++)
    #pragma unroll
    for (int ni=0;ni<2;ni++) acc[mi][ni] = (f32x4){0.f,0.f,0.f,0.f};
  #pragma unroll
  for (int kk = 0; kk < 128; kk += 32){
    bf16x8 af[4], bv[2];
    #pragma unroll
    for (int mi=0;mi<4;mi++) af[mi] = ldb16(&sX[mi*16 + fr][kk + fq*8]);
    #pragma unroll
    for (int ni=0;ni<2;ni++) bv[ni] = ldb16(&sRt[nw + ni*16 + fr][kk + fq*8]);
    #pragma unroll
    for (int mi=0;mi<4;mi++)
      #pragma unroll
      for (int ni=0;ni<2;ni++)
        acc[mi][ni] = MFMA16(af[mi], bv[ni], acc[mi][ni]);
  }
  #pragma unroll
  for (int mi=0;mi<4;mi++)
    #pragma unroll
    for (int ni=0;ni<2;ni++)
      #pragma unroll
      for (int rg=0;rg<4;rg++){
        int m = m0 + mi*16 + fq*4 + rg;
        int n = g*128 + nw + ni*16 + fr;
        Y[(size_t)m * LD + n] = f2bf(acc[mi][ni][rg]);
      }
}

// ---------------- 256x256 8-wave GEMM, int4 B dequanted global->reg (no LDS for B) ----------------
// A (bf16) via global_load_lds (pre-swizzled src) into 2x32KB dbuf; per wave 128x64 out.
// Per K-tile: {ADMA(t+1) | dequant rB(t)->bv | loadB(t+1) | 64 MFMA | vmcnt(20) | bar}.
// vmcnt(20) retires exactly the 4 A-DMA insts; the 20 B+scale loads stay in flight.
template<bool PARTIAL, bool OUT_BF16>
__global__ __launch_bounds__(512) void gemm_deq(
    const u16* __restrict__ A, const int* __restrict__ QW,
    const float* __restrict__ SC, void* __restrict__ Cout,
    int N, int K, int kc, int nN)
{
  __shared__ u16 sA[2][16384];   // [256][64] bf16, byte^=(row&7)<<4
  const int tid = threadIdx.x;
  const int lane = tid & 63, w = tid >> 6;
  const int nblk = gridDim.x, q8 = nblk >> 3, b = blockIdx.x;
  const int l = (b & 7) * q8 + (b >> 3);
  const int mt = l & 3, rest = l >> 2;
  const int nt = rest % nN, z = rest / nN;
  const int bm0 = mt * 256, bn0 = nt * 256;
  const int kbase = z * kc;
  const int KG = K >> 7;
  const int nkt = kc >> 6;

  f32x4 acc[8][4];
  #pragma unroll
  for (int i=0;i<8;i++)
    #pragma unroll
    for (int j=0;j<4;j++) acc[i][j] = (f32x4){0.f,0.f,0.f,0.f};

  const int wr = (w >> 2) * 128, wc = (w & 3) * 64;
  const int fr = lane & 15, fq = lane >> 4;

  // A-DMA: wave w covers rows [w*32, w*32+32), 4 insts of 8 rows
  const int l8 = lane >> 3;
  const size_t K2 = (size_t)K * 2;
  const char* gA0 = (const char*)A
      + ((size_t)(bm0 + w*32 + l8) * K + (size_t)kbase) * 2
      + (((lane & 7) * 16) ^ (l8 << 4));

  // B row pointers: lane's 4 fragment rows
  const int*   rowp[4];
  const float* scp[4];
  #pragma unroll
  for (int ni=0;ni<4;ni++){
    int n = bn0 + wc + ni*16 + fr;
    rowp[ni] = QW + (size_t)n * K + kbase;
    scp[ni]  = SC + (size_t)n * KG;
  }
  const int cq = fq * 8;

  int32x4 rB[4][2][2];
  float   rSc[4];
  bf16x8  bv[4][2];

  auto ADMA = [&](int kt, int c){
    const char* g = gA0 + (size_t)kt * 128;
    char* lb = (char*)&sA[c][0] + (w*32) * 128;
    #pragma unroll
    for (int i=0;i<4;i++)
      gload_lds16(g + (size_t)(i*8) * K2, lb + i*1024);
  };
  auto loadB = [&](int kt){
    const int k0 = kt * 64;
    #pragma unroll
    for (int ni=0;ni<4;ni++)
      #pragma unroll
      for (int kk=0;kk<2;kk++){
        const int* p = rowp[ni] + k0 + kk*32 + cq;
        rB[ni][kk][0] = *(const int32x4*)(p);
        rB[ni][kk][1] = *(const int32x4*)(p + 4);
      }
    const int g = (kbase + k0) >> 7;
    #pragma unroll
    for (int ni=0;ni<4;ni++) rSc[ni] = scp[ni][g];
  };
  auto DEQ = [&](){
    #pragma unroll
    for (int ni=0;ni<4;ni++){
      float s = rSc[ni], ns = -8.f * s;
      #pragma unroll
      for (int kk=0;kk<2;kk++){
        int32x4 a = rB[ni][kk][0], c2 = rB[ni][kk][1];
        bf16x8 o;
        o[0]=(__bf16)fmaf((float)a.x ,s,ns);
        o[1]=(__bf16)fmaf((float)a.y ,s,ns);
        o[2]=(__bf16)fmaf((float)a.z ,s,ns);
        o[3]=(__bf16)fmaf((float)a.w ,s,ns);
        o[4]=(__bf16)fmaf((float)c2.x,s,ns);
        o[5]=(__bf16)fmaf((float)c2.y,s,ns);
        o[6]=(__bf16)fmaf((float)c2.z,s,ns);
        o[7]=(__bf16)fmaf((float)c2.w,s,ns);
        bv[ni][kk] = o;
      }
    }
  };

  // ---- prologue ----
  ADMA(0, 0);
  __builtin_amdgcn_sched_barrier(0);
  loadB(0);
  __builtin_amdgcn_sched_barrier(0);
  asm volatile("s_waitcnt vmcnt(20)" ::: "memory");   // A(0) landed
  __builtin_amdgcn_s_barrier();
  __builtin_amdgcn_sched_barrier(0);

  int cb = 0;
  for (int t = 0; t < nkt; ++t){
    const bool more = (t + 1) < nkt;
    if (more){ ADMA(t+1, cb ^ 1); __builtin_amdgcn_sched_barrier(0); }
    DEQ();                                   // consumes rB(t) (compiler waits)
    if (more){ loadB(t+1); __builtin_amdgcn_sched_barrier(0); }
    __builtin_amdgcn_s_setprio(1);
    #pragma unroll
    for (int kk=0;kk<2;kk++){
      bf16x8 af[8];
      #pragma unroll
      for (int mi=0;mi<8;mi++){
        int r = wr + mi*16 + fr;
        af[mi] = *(const bf16x8*)((const char*)&sA[cb][0] + r*128 +
                  ((kk*64 + fq*16) ^ ((r & 7) << 4)));
      }
      #pragma unroll
      for (int mi=0;mi<8;mi++)
        #pragma unroll
        for (int ni=0;ni<4;ni++)
          acc[mi][ni] = MFMA16(af[mi], bv[ni][kk], acc[mi][ni]);
    }
    __builtin_amdgcn_s_setprio(0);
    if (more){
      asm volatile("s_waitcnt vmcnt(20)" ::: "memory");  // A(t+1) landed; B stays in flight
      __builtin_amdgcn_s_barrier();
      __builtin_amdgcn_sched_barrier(0);
      cb ^= 1;
    }
  }

  #pragma unroll
  for (int mi=0;mi<8;mi++)
    #pragma unroll
    for (int ni=0;ni<4;ni++)
      #pragma unroll
      for (int rg=0;rg<4;rg++){
        size_t m = bm0 + wr + mi*16 + fq*4 + rg;
        size_t n = bn0 + wc + ni*16 + fr;
        float v = acc[mi][ni][rg];
        if (PARTIAL)          ((float*)Cout)[((size_t)z*1024 + m) * N + n] = v;
        else if (OUT_BF16)    ((u16*)Cout)[m * N + n] = f2bf(v);
        else                  ((float*)Cout)[m * N + n] = v;
      }
}

// ---------------- split-K reduce (f32x4), optional addend, f32 or bf16 out ----------------
__global__ __launch_bounds__(256) void reduce_splits(
    const float* __restrict__ P, int nsplit, int n,
    const float* __restrict__ addend, float* __restrict__ outf, u16* __restrict__ outb)
{
  size_t base = ((size_t)blockIdx.x*256 + threadIdx.x) * 4;
  if (base >= (size_t)n) return;
  f32x4 s = *(const f32x4*)&P[base];
  for (int j = 1; j < nsplit; ++j)
    s += *(const f32x4*)&P[(size_t)j*n + base];
  if (addend) s += *(const f32x4*)&addend[base];
  if (outb){
    short4v o;
    #pragma unroll
    for (int e=0;e<4;e++) o[e] = (short)f2bf(s[e]);
    *(short4v*)&outb[base] = o;
  } else {
    *(f32x4*)&outf[base] = s;
  }
}

// ---------------- per-(t,head) RMSNorm over D=128 + RoPE, bf16 out ----------------
__global__ __launch_bounds__(64) void qknorm_rope_kernel(
    const float* __restrict__ in, const float* __restrict__ w,
    const int* __restrict__ pos, u16* __restrict__ out, int nh)
{
  const int t = blockIdx.x, h = blockIdx.y, j = threadIdx.x;
  const float* row = in + ((size_t)t * nh + h) * 128;
  float x1 = row[j], x2 = row[j + 64];
  float ss = x1*x1 + x2*x2;
  #pragma unroll
  for (int off = 32; off; off >>= 1) ss += __shfl_xor(ss, off);
  float rn = rsqrtf(ss / 128.f + 1e-6f);
  float xn1 = x1 * rn * w[j], xn2 = x2 * rn * w[j + 64];
  float inv = exp2f(-(float)j * (19.93156856932417f / 64.f));
  float f = (float)pos[t] * inv;
  float sv, cv; sincosf(f, &sv, &cv);
  u16* orow = out + ((size_t)t * nh + h) * 128;
  orow[j]      = f2bf(xn1 * cv - xn2 * sv);
  orow[j + 64] = f2bf(xn2 * cv + xn1 * sv);
}

// ---------------- causal GQA flash attention, D=128, KV tiles of 32 ----------------
__global__ __launch_bounds__(256) void attn_kernel(
    const u16* __restrict__ Q, const u16* __restrict__ Kc,
    const u16* __restrict__ Vc, u16* __restrict__ O)
{
  __shared__ u16 sK[32][128];
  __shared__ u16 sVt[128][32];
  __shared__ u16 sP[4][16][32];
  const int qt = blockIdx.x, h = blockIdx.y, kvh = h >> 2;
  const int tid = threadIdx.x, lane = tid & 63, w = tid >> 6;
  const int fr = lane & 15, fq = lane >> 4;
  const int r0 = qt*64 + w*16;
  const float scale = 0.08838834764831845f;
  bf16x8 aq[4];
  #pragma unroll
  for (int kd=0;kd<4;kd++)
    aq[kd] = ldb16(&Q[(size_t)(r0 + fr) * 4096 + h*128 + kd*32 + fq*8]);
  f32x4 accO[8];
  #pragma unroll
  for (int ni=0;ni<8;ni++) accO[ni] = (f32x4){0.f,0.f,0.f,0.f};
  float mrow[4] = {-1e30f,-1e30f,-1e30f,-1e30f};
  float lrow[4] = {0.f,0.f,0.f,0.f};
  const int ntiles = (qt + 1) * 2;
  for (int jt = 0; jt < ntiles; ++jt){
    __syncthreads();
    #pragma unroll
    for (int i=0;i<2;i++){
      int vid = i*256 + tid, r = vid >> 4, c = (vid & 15) * 8;
      *(short8*)&sK[r][c] = *(const short8*)&Kc[(size_t)(jt*32 + r) * 1024 + kvh*128 + c];
      short8 vv = *(const short8*)&Vc[(size_t)(jt*32 + r) * 1024 + kvh*128 + c];
      const u16* pv = (const u16*)&vv;
      #pragma unroll
      for (int e=0;e<8;e++) sVt[c + e][r] = pv[e];
    }
    __syncthreads();
    f32x4 accS[2]; accS[0] = (f32x4){0.f,0.f,0.f,0.f}; accS[1] = accS[0];
    #pragma unroll
    for (int kd=0;kd<4;kd++){
      #pragma unroll
      for (int ni=0;ni<2;ni++){
        bf16x8 bk = ldb16(&sK[ni*16 + fr][kd*32 + fq*8]);
        accS[ni] = MFMA16(aq[kd], bk, accS[ni]);
      }
    }
    float s[2][4];
    #pragma unroll
    for (int ni=0;ni<2;ni++)
      #pragma unroll
      for (int rg=0;rg<4;rg++){
        int row = r0 + fq*4 + rg, col = jt*32 + ni*16 + fr;
        float v = accS[ni][rg] * scale;
        s[ni][rg] = (col <= row) ? v : -1e30f;
      }
    float alpha[4];
    #pragma unroll
    for (int rg=0;rg<4;rg++){
      float mx = fmaxf(s[0][rg], s[1][rg]);
      #pragma unroll
      for (int off=1; off<16; off<<=1) mx = fmaxf(mx, __shfl_xor(mx, off, 16));
      float mnew = fmaxf(mrow[rg], mx);
      alpha[rg] = __expf(mrow[rg] - mnew);
      mrow[rg] = mnew;
      float p0 = __expf(s[0][rg] - mnew), p1 = __expf(s[1][rg] - mnew);
      s[0][rg] = p0; s[1][rg] = p1;
      float ps = p0 + p1;
      #pragma unroll
      for (int off=1; off<16; off<<=1) ps += __shfl_xor(ps, off, 16);
      lrow[rg] = lrow[rg] * alpha[rg] + ps;
    }
    #pragma unroll
    for (int ni=0;ni<2;ni++)
      #pragma unroll
      for (int rg=0;rg<4;rg++)
        sP[w][fq*4 + rg][ni*16 + fr] = f2bf(s[ni][rg]);
    __syncthreads();
    #pragma unroll
    for (int ni=0;ni<8;ni++)
      #pragma unroll
      for (int rg=0;rg<4;rg++) accO[ni][rg] *= alpha[rg];
    bf16x8 ap = ldb16(&sP[w][fr][fq*8]);
    #pragma unroll
    for (int ni=0;ni<8;ni++){
      bf16x8 bv = ldb16(&sVt[ni*16 + fr][fq*8]);
      accO[ni] = MFMA16(ap, bv, accO[ni]);
    }
  }
  #pragma unroll
  for (int ni=0;ni<8;ni++)
    #pragma unroll
    for (int rg=0;rg<4;rg++){
      int row = r0 + fq*4 + rg, col = h*128 + ni*16 + fr;
      O[(size_t)row * 4096 + col] = f2bf(accO[ni][rg] / lrow[rg]);
    }
}

// ---------------- silu(gate)*up ----------------
__global__ __launch_bounds__(256) void silu_mul_kernel(
    const u16* __restrict__ g, const u16* __restrict__ u, u16* __restrict__ o, int n)
{
  int i = blockIdx.x * 256 + threadIdx.x;
  if (i < n){
    float gv = bf2f(g[i]), uv = bf2f(u[i]);
    o[i] = f2bf(gv / (1.f + __expf(-gv)) * uv);
  }
}

extern "C" void kernel_launch(void* const* d_in, const int* in_sizes, int n_in,
                              void* d_out, int out_size, void* d_ws, size_t ws_size,
                              hipStream_t stream)
{
  const int*   positions = (const int*)  d_in[0];
  const float* hs    = (const float*)d_in[1];
  const float* resid = (const float*)d_in[2];
  const float* w_in  = (const float*)d_in[3];
  const float* w_post= (const float*)d_in[4];
  const float* w_qn  = (const float*)d_in[5];
  const float* w_kn  = (const float*)d_in[6];
  const float* R_q = (const float*)d_in[7];
  const int*   qw_q= (const int*)  d_in[8];
  const float* sc_q= (const float*)d_in[9];
  const float* R_k = (const float*)d_in[10];
  const int*   qw_k= (const int*)  d_in[11];
  const float* sc_k= (const float*)d_in[12];
  const float* R_v = (const float*)d_in[13];
  const int*   qw_v= (const int*)  d_in[14];
  const float* sc_v= (const float*)d_in[15];
  const float* R_o = (const float*)d_in[16];
  const int*   qw_o= (const int*)  d_in[17];
  const float* sc_o= (const float*)d_in[18];
  const float* R_g = (const float*)d_in[19];
  const int*   qw_g= (const int*)  d_in[20];
  const float* sc_g= (const float*)d_in[21];
  const float* R_u = (const float*)d_in[22];
  const int*   qw_u= (const int*)  d_in[23];
  const float* sc_u= (const float*)d_in[24];
  const float* R_d = (const float*)d_in[25];
  const int*   qw_d= (const int*)  d_in[26];
  const float* sc_d= (const float*)d_in[27];
  (void)in_sizes; (void)n_in; (void)out_size; (void)ws_size;

  char* wsp = (char*)d_ws; size_t off = 0;
  auto alloc = [&](size_t bytes)->void*{
    void* p = wsp + off; off += (bytes + 255) & ~(size_t)255; return p;
  };
  float* res  = (float*)alloc((size_t)T_*H_*4);       // 16MB
  u16*   xbf  = (u16*)  alloc((size_t)T_*H_*2);       // 8MB
  u16*   xrA  = (u16*)  alloc((size_t)T_*H_*2);       // 8MB
  u16*   xrB  = (u16*)  alloc((size_t)T_*H_*2);       // 8MB
  u16*   xrC  = (u16*)  alloc((size_t)T_*H_*2);       // 8MB
  float* qf   = (float*)alloc((size_t)T_*4096*4);     // 16MB
  float* kf   = (float*)alloc((size_t)T_*1024*4);     // 4MB
  u16*   qbf  = (u16*)  alloc((size_t)T_*4096*2);     // 8MB
  u16*   kbf  = (u16*)  alloc((size_t)T_*1024*2);     // 2MB
  u16*   vbf  = (u16*)  alloc((size_t)T_*1024*2);     // 2MB
  u16*   abf  = (u16*)  alloc((size_t)T_*4096*2);     // 8MB
  u16*   gbf  = (u16*)  alloc((size_t)T_*I_*2);       // 24MB
  u16*   ubf  = (u16*)  alloc((size_t)T_*I_*2);       // 24MB
  u16*   hbf  = (u16*)  alloc((size_t)T_*I_*2);       // 24MB
  u16*   hrbf = gbf;   // gate buffer free after silu_mul

  // split-K partial regions reuse dead buffers (all sequential on one stream):
  float* pQKV = (float*)gbf;   // gbf..hbf (72MB) dead until gate-GEMM
  float* pO   = (float*)gbf;
  float* pD   = (float*)wsp;   // res..qf (64MB) dead at down-proj

  float* h2   = (float*)d_out;
  float* res2 = (float*)d_out + (size_t)T_*H_;

  addnorm_kernel<<<T_, 256, 0, stream>>>(hs, resid, w_in, res, xbf);
  rot_kernel<<<dim3(16,32),256,0,stream>>>(xbf, R_q, xrA, H_);
  rot_kernel<<<dim3(16,32),256,0,stream>>>(xbf, R_k, xrB, H_);
  rot_kernel<<<dim3(16,32),256,0,stream>>>(xbf, R_v, xrC, H_);
  // q: N=4096 (nN=16), z=4 (kc=1024) -> 256 blocks
  gemm_deq<true ,false><<<256,512,0,stream>>>(xrA, qw_q, sc_q, pQKV, 4096, 4096, 1024, 16);
  reduce_splits<<<(T_*4096)/1024,256,0,stream>>>(pQKV, 4, T_*4096, nullptr, qf, nullptr);
  // k: N=1024 (nN=4), z=8 (kc=512) -> 128 blocks
  gemm_deq<true ,false><<<128,512,0,stream>>>(xrB, qw_k, sc_k, pQKV, 1024, 4096, 512, 4);
  reduce_splits<<<(T_*1024)/1024,256,0,stream>>>(pQKV, 8, T_*1024, nullptr, kf, nullptr);
  // v: N=1024, z=8 -> 128 blocks, bf16 out via reduce
  gemm_deq<true ,false><<<128,512,0,stream>>>(xrC, qw_v, sc_v, pQKV, 1024, 4096, 512, 4);
  reduce_splits<<<(T_*1024)/1024,256,0,stream>>>(pQKV, 8, T_*1024, nullptr, nullptr, vbf);
  qknorm_rope_kernel<<<dim3(T_,NH_ ),64,0,stream>>>(qf, w_qn, positions, qbf, NH_);
  qknorm_rope_kernel<<<dim3(T_,NKV_),64,0,stream>>>(kf, w_kn, positions, kbf, NKV_);
  attn_kernel<<<dim3(16,32),256,0,stream>>>(qbf, kbf, vbf, abf);
  rot_kernel<<<dim3(16,32),256,0,stream>>>(abf, R_o, xrA, H_);
  // o: z=4 (kc=1024) -> 256 blocks; reduce fuses +res -> res2
  gemm_deq<true ,false><<<256,512,0,stream>>>(xrA, qw_o, sc_o, pO, 4096, 4096, 1024, 16);
  reduce_splits<<<(T_*4096)/1024,256,0,stream>>>(pO, 4, T_*4096, res, res2, nullptr);
  addnorm_kernel<<<T_,256,0,stream>>>(res2, nullptr, w_post, nullptr, xbf);
  rot_kernel<<<dim3(16,32),256,0,stream>>>(xbf, R_g, xrA, H_);
  rot_kernel<<<dim3(16,32),256,0,stream>>>(xbf, R_u, xrB, H_);
  // gate/up: N=12288 (nN=48), z=1 -> 192 blocks, direct bf16 out
  gemm_deq<false,true ><<<192,512,0,stream>>>(xrA, qw_g, sc_g, gbf, 12288, 4096, 4096, 48);
  gemm_deq<false,true ><<<192,512,0,stream>>>(xrB, qw_u, sc_u, ubf, 12288, 4096, 4096, 48);
  silu_mul_kernel<<<(T_*I_)/256,256,0,stream>>>(gbf, ubf, hbf, T_*I_);
  rot_kernel<<<dim3(16,96),256,0,stream>>>(hbf, R_d, hrbf, I_);
  // down: N=4096 (nN=16), K=12288, z=4 (kc=3072) -> 256 blocks
  gemm_deq<true ,false><<<256,512,0,stream>>>(hrbf, qw_d, sc_d, pD, 4096, 12288, 3072, 16);
  reduce_splits<<<(T_*4096)/1024,256,0,stream>>>(pD, 4, T_*4096, nullptr, h2, nullptr);
}

// Round 7
// 1011.663 us; speedup vs baseline: 2.5124x; 2.5124x over previous
//
#include <hip/hip_runtime.h>

typedef unsigned short u16;
typedef __attribute__((ext_vector_type(4))) float   f32x4;
typedef __attribute__((ext_vector_type(8))) __bf16  bf16x8;
typedef __attribute__((ext_vector_type(4))) __bf16  bf16x4;
typedef __attribute__((ext_vector_type(8))) short   short8;
typedef __attribute__((ext_vector_type(4))) int     int32x4;
typedef __attribute__((ext_vector_type(4))) short   short4v;

#define MFMA16(a,b,c) __builtin_amdgcn_mfma_f32_16x16x32_bf16(a,b,c,0,0,0)

static __device__ __forceinline__ u16 f2bf(float f){
  unsigned u = __builtin_bit_cast(unsigned, f);
  return (u16)((u + 0x7fffu + ((u >> 16) & 1u)) >> 16);
}
static __device__ __forceinline__ float bf2f(u16 h){
  return __builtin_bit_cast(float, ((unsigned)h) << 16);
}
static __device__ __forceinline__ bf16x8 ldb16(const u16* p){
  return __builtin_bit_cast(bf16x8, *(const short8*)p);
}
static __device__ __forceinline__ void gload_lds16(const void* g, void* l){
  __builtin_amdgcn_global_load_lds(
      reinterpret_cast<const __attribute__((address_space(1))) unsigned int*>(
          reinterpret_cast<unsigned long long>(g)),
      reinterpret_cast<__attribute__((address_space(3))) unsigned int*>(
          reinterpret_cast<unsigned long long>(l)),
      16, 0, 0);
}

static constexpr int T_ = 1024, H_ = 4096, NH_ = 32, NKV_ = 8, I_ = 12288;

// ---------------- fused (optional add) + RMSNorm over H=4096, bf16 out ----------------
__global__ __launch_bounds__(256) void addnorm_kernel(
    const float* __restrict__ a, const float* __restrict__ b,
    const float* __restrict__ w, float* __restrict__ res_out,
    u16* __restrict__ x_out)
{
  const int t = blockIdx.x, tid = threadIdx.x;
  __shared__ float red[4];
  float vals[16]; float ss = 0.f;
  const size_t base = (size_t)t * H_;
  #pragma unroll
  for (int i = 0; i < 16; ++i){
    int c = tid + i*256;
    float v = a[base + c];
    if (b) v += b[base + c];
    vals[i] = v; ss += v*v;
  }
  #pragma unroll
  for (int off = 32; off; off >>= 1) ss += __shfl_xor(ss, off);
  if ((tid & 63) == 0) red[tid >> 6] = ss;
  __syncthreads();
  float tot = red[0] + red[1] + red[2] + red[3];
  float rn = rsqrtf(tot / (float)H_ + 1e-6f);
  #pragma unroll
  for (int i = 0; i < 16; ++i){
    int c = tid + i*256;
    if (res_out) res_out[base + c] = vals[i];
    x_out[base + c] = f2bf(vals[i] * rn * w[c]);
  }
}

// ---------------- block-diagonal rotation ----------------
__global__ __launch_bounds__(256) void rot_kernel(
    const u16* __restrict__ X, const float* __restrict__ R,
    u16* __restrict__ Y, int LD)
{
  __shared__ u16 sX[64][136];
  __shared__ u16 sRt[128][136];   // sRt[j][i] = R[g][i][j]
  const int g = blockIdx.y, m0 = blockIdx.x * 64, tid = threadIdx.x;
  #pragma unroll
  for (int i = 0; i < 4; ++i){
    int vid = i*256 + tid, r = vid >> 4, c = (vid & 15) * 8;
    *(short8*)&sX[r][c] = *(const short8*)&X[(size_t)(m0 + r) * LD + g*128 + c];
  }
  const float* Rg = R + (size_t)g * 16384;
  #pragma unroll
  for (int it = 0; it < 16; ++it){
    int idx = it*256 + tid;
    int i = idx >> 5, j4 = (idx & 31) * 4;
    float4 v = *(const float4*)&Rg[i*128 + j4];
    sRt[j4  ][i] = f2bf(v.x);
    sRt[j4+1][i] = f2bf(v.y);
    sRt[j4+2][i] = f2bf(v.z);
    sRt[j4+3][i] = f2bf(v.w);
  }
  __syncthreads();
  const int lane = tid & 63, w = tid >> 6;
  const int fr = lane & 15, fq = lane >> 4, nw = w * 32;
  f32x4 acc[4][2];
  #pragma unroll
  for (int mi=0;mi<4;mi++)
    #pragma unroll
    for (int ni=0;ni<2;ni++) acc[mi][ni] = (f32x4){0.f,0.f,0.f,0.f};
  #pragma unroll
  for (int kk = 0; kk < 128; kk += 32){
    bf16x8 af[4], bv[2];
    #pragma unroll
    for (int mi=0;mi<4;mi++) af[mi] = ldb16(&sX[mi*16 + fr][kk + fq*8]);
    #pragma unroll
    for (int ni=0;ni<2;ni++) bv[ni] = ldb16(&sRt[nw + ni*16 + fr][kk + fq*8]);
    #pragma unroll
    for (int mi=0;mi<4;mi++)
      #pragma unroll
      for (int ni=0;ni<2;ni++)
        acc[mi][ni] = MFMA16(af[mi], bv[ni], acc[mi][ni]);
  }
  #pragma unroll
  for (int mi=0;mi<4;mi++)
    #pragma unroll
    for (int ni=0;ni<2;ni++)
      #pragma unroll
      for (int rg=0;rg<4;rg++){
        int m = m0 + mi*16 + fq*4 + rg;
        int n = g*128 + nw + ni*16 + fr;
        Y[(size_t)m * LD + n] = f2bf(acc[mi][ni][rg]);
      }
}

// ---------------- 256 x (NF*64) 8-wave GEMM, fused int4 dequant, 1 barrier/K-tile ----------------
// A (bf16) via global_load_lds (pre-swizzled src) into 2x32KB dbuf.
// B int4 reg-staged ONCE through LDS (dequant->ds_write), double-buffered.
// Per tile: {loadB(t+1)+ADMA(t+1) | MFMA kk=0 | vmcnt(4)+storeB->buf^1 | MFMA kk=1 |
//            vmcnt(0)+lgkm(0) | barrier | swap}. Wave-tile 128 x NF*16.
template<int NF, bool PARTIAL, bool OUT_BF16>
__global__ __launch_bounds__(512, 1) void gemm_deq(
    const u16* __restrict__ A, const int* __restrict__ QW,
    const float* __restrict__ SC, void* __restrict__ Cout,
    int N, int K, int kc, int nN)
{
  __shared__ u16 sA[2][16384];        // [256][64] bf16, byte^=(row&7)<<4
  __shared__ u16 sB[2][NF * 4096];    // [NF*64][64] bf16, same swizzle
  const int tid = threadIdx.x;
  const int lane = tid & 63, w = tid >> 6;
  const int nblk = gridDim.x, q8 = nblk >> 3, b = blockIdx.x;
  const int l = (b & 7) * q8 + (b >> 3);
  const int mt = l & 3, rest = l >> 2;
  const int nt = rest % nN, z = rest / nN;
  const int bm0 = mt * 256, bn0 = nt * (NF * 64);
  const int kbase = z * kc;
  const int KG = K >> 7;
  const int nkt = kc >> 6;

  f32x4 acc[8][NF];
  #pragma unroll
  for (int i=0;i<8;i++)
    #pragma unroll
    for (int j=0;j<NF;j++) acc[i][j] = (f32x4){0.f,0.f,0.f,0.f};

  const int wr = (w >> 2) * 128, wc = (w & 3) * (NF * 16);
  const int fr = lane & 15, fq = lane >> 4;

  // ---- A DMA (validated round 6): wave w covers rows [w*32, w*32+32) ----
  const int l8 = lane >> 3;
  const size_t K2 = (size_t)K * 2;
  const char* gA0 = (const char*)A
      + ((size_t)(bm0 + w*32 + l8) * K + (size_t)kbase) * 2
      + (((lane & 7) * 16) ^ (l8 << 4));
  auto ADMA = [&](int kt, int c){
    const char* g = gA0 + (size_t)kt * 128;
    char* lb = (char*)&sA[c][0] + (w*32) * 128;
    #pragma unroll
    for (int i=0;i<4;i++)
      gload_lds16(g + (size_t)(i*8) * K2, lb + i*1024);
  };

  // ---- B staging: thread covers rows (tid>>4)+32i (i<2*NF), int-cols (tid&15)*4 ----
  const int rBr = tid >> 4, cB4 = (tid & 15) * 4;
  const int* gB0 = QW + (size_t)(bn0 + rBr) * K + kbase + cB4;
  const float* gS0 = SC + (size_t)(bn0 + rBr) * KG;
  const int sBx = (cB4 * 2) ^ ((rBr & 7) << 4);   // (r&7) invariant under +32i

  int32x4 rB[2*NF];
  float   rS[2*NF];
  auto loadB = [&](int kt){
    const int* gb = gB0 + kt*64;
    const int g = (kbase + kt*64) >> 7;
    const float* ps = gS0 + g;
    #pragma unroll
    for (int i=0;i<2*NF;i++){
      rB[i] = *(const int32x4*)(gb + (size_t)i*32*K);
      rS[i] = ps[(size_t)i*32*KG];
    }
  };
  auto storeB = [&](int c){
    #pragma unroll
    for (int i=0;i<2*NF;i++){
      float s = rS[i], ns = -8.f * s;
      bf16x4 o;
      o[0] = (__bf16)fmaf((float)rB[i].x, s, ns);
      o[1] = (__bf16)fmaf((float)rB[i].y, s, ns);
      o[2] = (__bf16)fmaf((float)rB[i].z, s, ns);
      o[3] = (__bf16)fmaf((float)rB[i].w, s, ns);
      *(bf16x4*)((char*)&sB[c][0] + (rBr + 32*i)*128 + sBx) = o;
    }
  };

  auto mfma_half = [&](int c, int kk){
    bf16x8 af[8], bv[NF];
    #pragma unroll
    for (int mi=0;mi<8;mi++){
      int r = wr + mi*16 + fr;
      af[mi] = *(const bf16x8*)((const char*)&sA[c][0] + r*128 +
                ((kk*64 + fq*16) ^ ((r & 7) << 4)));
    }
    #pragma unroll
    for (int ni=0;ni<NF;ni++){
      int r = wc + ni*16 + fr;
      bv[ni] = *(const bf16x8*)((const char*)&sB[c][0] + r*128 +
                ((kk*64 + fq*16) ^ ((r & 7) << 4)));
    }
    __builtin_amdgcn_s_setprio(1);
    #pragma unroll
    for (int mi=0;mi<8;mi++)
      #pragma unroll
      for (int ni=0;ni<NF;ni++)
        acc[mi][ni] = MFMA16(af[mi], bv[ni], acc[mi][ni]);
    __builtin_amdgcn_s_setprio(0);
  };

  // ---- prologue: stage tile 0 into buffers [0] ----
  loadB(0);                 // 4*NF vmem
  ADMA(0, 0);               // 4 vmem
  asm volatile("s_waitcnt vmcnt(4)" ::: "memory");   // B(0)+scales retired
  __builtin_amdgcn_sched_barrier(0);
  storeB(0);
  asm volatile("s_waitcnt vmcnt(0) lgkmcnt(0)" ::: "memory");
  __builtin_amdgcn_s_barrier();

  int cb = 0;
  for (int t = 0; t < nkt; ++t){
    const bool more = (t + 1) < nkt;
    if (more){
      loadB(t+1);
      ADMA(t+1, cb ^ 1);
      __builtin_amdgcn_sched_barrier(0);
    }
    mfma_half(cb, 0);
    if (more){
      asm volatile("s_waitcnt vmcnt(4)" ::: "memory");  // retire B(t+1); ADMA stays
      __builtin_amdgcn_sched_barrier(0);
      storeB(cb ^ 1);
    }
    mfma_half(cb, 1);
    if (more){
      asm volatile("s_waitcnt vmcnt(0) lgkmcnt(0)" ::: "memory");
      __builtin_amdgcn_sched_barrier(0);
      __builtin_amdgcn_s_barrier();
      cb ^= 1;
    }
  }

  #pragma unroll
  for (int mi=0;mi<8;mi++)
    #pragma unroll
    for (int ni=0;ni<NF;ni++)
      #pragma unroll
      for (int rg=0;rg<4;rg++){
        size_t m = bm0 + wr + mi*16 + fq*4 + rg;
        size_t n = bn0 + wc + ni*16 + fr;
        float v = acc[mi][ni][rg];
        if (PARTIAL)          ((float*)Cout)[((size_t)z*1024 + m) * N + n] = v;
        else if (OUT_BF16)    ((u16*)Cout)[m * N + n] = f2bf(v);
        else                  ((float*)Cout)[m * N + n] = v;
      }
}

// ---------------- split-K reduce (f32x4), optional addend, f32 or bf16 out ----------------
__global__ __launch_bounds__(256) void reduce_splits(
    const float* __restrict__ P, int nsplit, int n,
    const float* __restrict__ addend, float* __restrict__ outf, u16* __restrict__ outb)
{
  size_t base = ((size_t)blockIdx.x*256 + threadIdx.x) * 4;
  if (base >= (size_t)n) return;
  f32x4 s = *(const f32x4*)&P[base];
  for (int j = 1; j < nsplit; ++j)
    s += *(const f32x4*)&P[(size_t)j*n + base];
  if (addend) s += *(const f32x4*)&addend[base];
  if (outb){
    short4v o;
    #pragma unroll
    for (int e=0;e<4;e++) o[e] = (short)f2bf(s[e]);
    *(short4v*)&outb[base] = o;
  } else {
    *(f32x4*)&outf[base] = s;
  }
}

// ---------------- per-(t,head) RMSNorm over D=128 + RoPE, bf16 out ----------------
__global__ __launch_bounds__(64) void qknorm_rope_kernel(
    const float* __restrict__ in, const float* __restrict__ w,
    const int* __restrict__ pos, u16* __restrict__ out, int nh)
{
  const int t = blockIdx.x, h = blockIdx.y, j = threadIdx.x;
  const float* row = in + ((size_t)t * nh + h) * 128;
  float x1 = row[j], x2 = row[j + 64];
  float ss = x1*x1 + x2*x2;
  #pragma unroll
  for (int off = 32; off; off >>= 1) ss += __shfl_xor(ss, off);
  float rn = rsqrtf(ss / 128.f + 1e-6f);
  float xn1 = x1 * rn * w[j], xn2 = x2 * rn * w[j + 64];
  float inv = exp2f(-(float)j * (19.93156856932417f / 64.f));
  float f = (float)pos[t] * inv;
  float sv, cv; sincosf(f, &sv, &cv);
  u16* orow = out + ((size_t)t * nh + h) * 128;
  orow[j]      = f2bf(xn1 * cv - xn2 * sv);
  orow[j + 64] = f2bf(xn2 * cv + xn1 * sv);
}

// ---------------- causal GQA flash attention, D=128, KV tiles of 32 ----------------
__global__ __launch_bounds__(256) void attn_kernel(
    const u16* __restrict__ Q, const u16* __restrict__ Kc,
    const u16* __restrict__ Vc, u16* __restrict__ O)
{
  __shared__ u16 sK[32][128];
  __shared__ u16 sVt[128][32];
  __shared__ u16 sP[4][16][32];
  const int qt = blockIdx.x, h = blockIdx.y, kvh = h >> 2;
  const int tid = threadIdx.x, lane = tid & 63, w = tid >> 6;
  const int fr = lane & 15, fq = lane >> 4;
  const int r0 = qt*64 + w*16;
  const float scale = 0.08838834764831845f;
  bf16x8 aq[4];
  #pragma unroll
  for (int kd=0;kd<4;kd++)
    aq[kd] = ldb16(&Q[(size_t)(r0 + fr) * 4096 + h*128 + kd*32 + fq*8]);
  f32x4 accO[8];
  #pragma unroll
  for (int ni=0;ni<8;ni++) accO[ni] = (f32x4){0.f,0.f,0.f,0.f};
  float mrow[4] = {-1e30f,-1e30f,-1e30f,-1e30f};
  float lrow[4] = {0.f,0.f,0.f,0.f};
  const int ntiles = (qt + 1) * 2;
  for (int jt = 0; jt < ntiles; ++jt){
    __syncthreads();
    #pragma unroll
    for (int i=0;i<2;i++){
      int vid = i*256 + tid, r = vid >> 4, c = (vid & 15) * 8;
      *(short8*)&sK[r][c] = *(const short8*)&Kc[(size_t)(jt*32 + r) * 1024 + kvh*128 + c];
      short8 vv = *(const short8*)&Vc[(size_t)(jt*32 + r) * 1024 + kvh*128 + c];
      const u16* pv = (const u16*)&vv;
      #pragma unroll
      for (int e=0;e<8;e++) sVt[c + e][r] = pv[e];
    }
    __syncthreads();
    f32x4 accS[2]; accS[0] = (f32x4){0.f,0.f,0.f,0.f}; accS[1] = accS[0];
    #pragma unroll
    for (int kd=0;kd<4;kd++){
      #pragma unroll
      for (int ni=0;ni<2;ni++){
        bf16x8 bk = ldb16(&sK[ni*16 + fr][kd*32 + fq*8]);
        accS[ni] = MFMA16(aq[kd], bk, accS[ni]);
      }
    }
    float s[2][4];
    #pragma unroll
    for (int ni=0;ni<2;ni++)
      #pragma unroll
      for (int rg=0;rg<4;rg++){
        int row = r0 + fq*4 + rg, col = jt*32 + ni*16 + fr;
        float v = accS[ni][rg] * scale;
        s[ni][rg] = (col <= row) ? v : -1e30f;
      }
    float alpha[4];
    #pragma unroll
    for (int rg=0;rg<4;rg++){
      float mx = fmaxf(s[0][rg], s[1][rg]);
      #pragma unroll
      for (int off=1; off<16; off<<=1) mx = fmaxf(mx, __shfl_xor(mx, off, 16));
      float mnew = fmaxf(mrow[rg], mx);
      alpha[rg] = __expf(mrow[rg] - mnew);
      mrow[rg] = mnew;
      float p0 = __expf(s[0][rg] - mnew), p1 = __expf(s[1][rg] - mnew);
      s[0][rg] = p0; s[1][rg] = p1;
      float ps = p0 + p1;
      #pragma unroll
      for (int off=1; off<16; off<<=1) ps += __shfl_xor(ps, off, 16);
      lrow[rg] = lrow[rg] * alpha[rg] + ps;
    }
    #pragma unroll
    for (int ni=0;ni<2;ni++)
      #pragma unroll
      for (int rg=0;rg<4;rg++)
        sP[w][fq*4 + rg][ni*16 + fr] = f2bf(s[ni][rg]);
    __syncthreads();
    #pragma unroll
    for (int ni=0;ni<8;ni++)
      #pragma unroll
      for (int rg=0;rg<4;rg++) accO[ni][rg] *= alpha[rg];
    bf16x8 ap = ldb16(&sP[w][fr][fq*8]);
    #pragma unroll
    for (int ni=0;ni<8;ni++){
      bf16x8 bv = ldb16(&sVt[ni*16 + fr][fq*8]);
      accO[ni] = MFMA16(ap, bv, accO[ni]);
    }
  }
  #pragma unroll
  for (int ni=0;ni<8;ni++)
    #pragma unroll
    for (int rg=0;rg<4;rg++){
      int row = r0 + fq*4 + rg, col = h*128 + ni*16 + fr;
      O[(size_t)row * 4096 + col] = f2bf(accO[ni][rg] / lrow[rg]);
    }
}

// ---------------- silu(gate)*up ----------------
__global__ __launch_bounds__(256) void silu_mul_kernel(
    const u16* __restrict__ g, const u16* __restrict__ u, u16* __restrict__ o, int n)
{
  int i = blockIdx.x * 256 + threadIdx.x;
  if (i < n){
    float gv = bf2f(g[i]), uv = bf2f(u[i]);
    o[i] = f2bf(gv / (1.f + __expf(-gv)) * uv);
  }
}

extern "C" void kernel_launch(void* const* d_in, const int* in_sizes, int n_in,
                              void* d_out, int out_size, void* d_ws, size_t ws_size,
                              hipStream_t stream)
{
  const int*   positions = (const int*)  d_in[0];
  const float* hs    = (const float*)d_in[1];
  const float* resid = (const float*)d_in[2];
  const float* w_in  = (const float*)d_in[3];
  const float* w_post= (const float*)d_in[4];
  const float* w_qn  = (const float*)d_in[5];
  const float* w_kn  = (const float*)d_in[6];
  const float* R_q = (const float*)d_in[7];
  const int*   qw_q= (const int*)  d_in[8];
  const float* sc_q= (const float*)d_in[9];
  const float* R_k = (const float*)d_in[10];
  const int*   qw_k= (const int*)  d_in[11];
  const float* sc_k= (const float*)d_in[12];
  const float* R_v = (const float*)d_in[13];
  const int*   qw_v= (const int*)  d_in[14];
  const float* sc_v= (const float*)d_in[15];
  const float* R_o = (const float*)d_in[16];
  const int*   qw_o= (const int*)  d_in[17];
  const float* sc_o= (const float*)d_in[18];
  const float* R_g = (const float*)d_in[19];
  const int*   qw_g= (const int*)  d_in[20];
  const float* sc_g= (const float*)d_in[21];
  const float* R_u = (const float*)d_in[22];
  const int*   qw_u= (const int*)  d_in[23];
  const float* sc_u= (const float*)d_in[24];
  const float* R_d = (const float*)d_in[25];
  const int*   qw_d= (const int*)  d_in[26];
  const float* sc_d= (const float*)d_in[27];
  (void)in_sizes; (void)n_in; (void)out_size; (void)ws_size;

  char* wsp = (char*)d_ws; size_t off = 0;
  auto alloc = [&](size_t bytes)->void*{
    void* p = wsp + off; off += (bytes + 255) & ~(size_t)255; return p;
  };
  float* res  = (float*)alloc((size_t)T_*H_*4);       // 16MB
  u16*   xbf  = (u16*)  alloc((size_t)T_*H_*2);       // 8MB
  u16*   xrA  = (u16*)  alloc((size_t)T_*H_*2);       // 8MB
  u16*   xrB  = (u16*)  alloc((size_t)T_*H_*2);       // 8MB
  u16*   xrC  = (u16*)  alloc((size_t)T_*H_*2);       // 8MB
  float* qf   = (float*)alloc((size_t)T_*4096*4);     // 16MB
  float* kf   = (float*)alloc((size_t)T_*1024*4);     // 4MB
  u16*   qbf  = (u16*)  alloc((size_t)T_*4096*2);     // 8MB
  u16*   kbf  = (u16*)  alloc((size_t)T_*1024*2);     // 2MB
  u16*   vbf  = (u16*)  alloc((size_t)T_*1024*2);     // 2MB
  u16*   abf  = (u16*)  alloc((size_t)T_*4096*2);     // 8MB
  u16*   gbf  = (u16*)  alloc((size_t)T_*I_*2);       // 24MB
  u16*   ubf  = (u16*)  alloc((size_t)T_*I_*2);       // 24MB
  u16*   hbf  = (u16*)  alloc((size_t)T_*I_*2);       // 24MB
  u16*   hrbf = gbf;   // gate buffer free after silu_mul

  // split-K partial regions reuse dead buffers (all sequential on one stream):
  float* pQKV = (float*)gbf;   // gbf..hbf (72MB) dead until gate-GEMM
  float* pO   = (float*)gbf;
  float* pD   = (float*)wsp;   // res..qf (64MB) dead at down-proj

  float* h2   = (float*)d_out;
  float* res2 = (float*)d_out + (size_t)T_*H_;

  addnorm_kernel<<<T_, 256, 0, stream>>>(hs, resid, w_in, res, xbf);
  rot_kernel<<<dim3(16,32),256,0,stream>>>(xbf, R_q, xrA, H_);
  rot_kernel<<<dim3(16,32),256,0,stream>>>(xbf, R_k, xrB, H_);
  rot_kernel<<<dim3(16,32),256,0,stream>>>(xbf, R_v, xrC, H_);
  // q: N=4096 (nN=16), z=4 (kc=1024) -> 256 blocks, 1/CU
  gemm_deq<4,true ,false><<<256,512,0,stream>>>(xrA, qw_q, sc_q, pQKV, 4096, 4096, 1024, 16);
  reduce_splits<<<(T_*4096)/1024,256,0,stream>>>(pQKV, 4, T_*4096, nullptr, qf, nullptr);
  // k: N=1024 (nN=4), z=8 (kc=512) -> 128 blocks
  gemm_deq<4,true ,false><<<128,512,0,stream>>>(xrB, qw_k, sc_k, pQKV, 1024, 4096, 512, 4);
  reduce_splits<<<(T_*1024)/1024,256,0,stream>>>(pQKV, 8, T_*1024, nullptr, kf, nullptr);
  // v: N=1024, z=8 -> 128 blocks, bf16 out via reduce
  gemm_deq<4,true ,false><<<128,512,0,stream>>>(xrC, qw_v, sc_v, pQKV, 1024, 4096, 512, 4);
  reduce_splits<<<(T_*1024)/1024,256,0,stream>>>(pQKV, 8, T_*1024, nullptr, nullptr, vbf);
  qknorm_rope_kernel<<<dim3(T_,NH_ ),64,0,stream>>>(qf, w_qn, positions, qbf, NH_);
  qknorm_rope_kernel<<<dim3(T_,NKV_),64,0,stream>>>(kf, w_kn, positions, kbf, NKV_);
  attn_kernel<<<dim3(16,32),256,0,stream>>>(qbf, kbf, vbf, abf);
  rot_kernel<<<dim3(16,32),256,0,stream>>>(abf, R_o, xrA, H_);
  // o: z=4 -> 256 blocks; reduce fuses +res -> res2
  gemm_deq<4,true ,false><<<256,512,0,stream>>>(xrA, qw_o, sc_o, pO, 4096, 4096, 1024, 16);
  reduce_splits<<<(T_*4096)/1024,256,0,stream>>>(pO, 4, T_*4096, res, res2, nullptr);
  addnorm_kernel<<<T_,256,0,stream>>>(res2, nullptr, w_post, nullptr, xbf);
  rot_kernel<<<dim3(16,32),256,0,stream>>>(xbf, R_g, xrA, H_);
  rot_kernel<<<dim3(16,32),256,0,stream>>>(xbf, R_u, xrB, H_);
  // gate/up: NF=3 (BN=192), nN=64 -> 256 blocks exactly, z=1, direct bf16 out
  gemm_deq<3,false,true ><<<256,512,0,stream>>>(xrA, qw_g, sc_g, gbf, 12288, 4096, 4096, 64);
  gemm_deq<3,false,true ><<<256,512,0,stream>>>(xrB, qw_u, sc_u, ubf, 12288, 4096, 4096, 64);
  silu_mul_kernel<<<(T_*I_)/256,256,0,stream>>>(gbf, ubf, hbf, T_*I_);
  rot_kernel<<<dim3(16,96),256,0,stream>>>(hbf, R_d, hrbf, I_);
  // down: N=4096 (nN=16), K=12288, z=4 (kc=3072) -> 256 blocks
  gemm_deq<4,true ,false><<<256,512,0,stream>>>(hrbf, qw_d, sc_d, pD, 4096, 12288, 3072, 16);
  reduce_splits<<<(T_*4096)/1024,256,0,stream>>>(pD, 4, T_*4096, nullptr, h2, nullptr);
}